// Round 6
// baseline (852.312 us; speedup 1.0000x reference)
//
#include <hip/hip_runtime.h>
#include <hip/hip_bf16.h>

#define NPB 32      // nodes per block in GEMM
#define PAD 64      // padded-CSR slots per node (P(deg>64 | Poisson(32)) ~ 1e-8)
#define OVF_CAP 4096

typedef float f32x2 __attribute__((ext_vector_type(2)));

__device__ __forceinline__ float b2f(__hip_bfloat16 v) { return __bfloat162float(v); }
// float-typed harness input that may be fp32 or bf16 (dt[0] selects)
__device__ __forceinline__ float ldf(const void* p, long i, int f32) {
    return f32 ? ((const float*)p)[i] : b2f(((const __hip_bfloat16*)p)[i]);
}
// pair load: elements 2*i2, 2*i2+1 of a float-typed input (fp32 or bf16)
__device__ __forceinline__ float bflo(unsigned u) { union { unsigned i; float f; } v; v.i = u << 16; return v.f; }
__device__ __forceinline__ float bfhi(unsigned u) { union { unsigned i; float f; } v; v.i = u & 0xffff0000u; return v.f; }
__device__ __forceinline__ float2 ldf2(const void* p, long i2, int f32) {
    if (f32) return ((const float2*)p)[i2];
    unsigned u = ((const unsigned*)p)[i2];
    return make_float2(bflo(u), bfhi(u));
}
// integer harness input that may be int32 or little-endian int64 (<2^31) (dt[1] selects)
__device__ __forceinline__ int ldi(const int* p, long i, int i32) {
    return i32 ? p[i] : p[2 * i];
}
__device__ __forceinline__ int rfl(int v) { return __builtin_amdgcn_readfirstlane(v); }
// pack two floats into one dword of 2 bf16 (lo = a, hi = b)
__device__ __forceinline__ unsigned pk2(float a, float b) {
    __hip_bfloat16 ha = __float2bfloat16(a), hb = __float2bfloat16(b);
    unsigned short ua = *(unsigned short*)&ha, ub = *(unsigned short*)&hb;
    return (unsigned)ua | ((unsigned)ub << 16);
}

// DPP-based butterfly add within a 16-lane row (pure VALU, no LDS pipe).
// CTRL: 0xB1 = quad_perm xor1, 0x4E = quad_perm xor2, 0x124 = row_ror:4, 0x128 = row_ror:8
template <int CTRL>
__device__ __forceinline__ float dpp_add(float v) {
    int s = __builtin_amdgcn_update_dpp(0, __float_as_int(v), CTRL, 0xF, 0xF, true);
    return v + __int_as_float(s);
}

// ---------------- zero ints (cnt + ovfcnt) + dt ----------------
__global__ void zero_i(int* __restrict__ a, long n, int* __restrict__ dt)
{
    long i = (long)blockIdx.x * 256 + threadIdx.x;
    long stride = (long)gridDim.x * 256;
    for (; i < n; i += stride) a[i] = 0;
    if (blockIdx.x == 0 && threadIdx.x == 0 && dt) { dt[0] = 0; dt[1] = 0; }
}

// failure-gated fp32 code write (ws-guard only)
__global__ void fail_stamp(float* __restrict__ out, float code)
{
    if (threadIdx.x == 0 && blockIdx.x == 0) out[0] = code;
}

// ---------------- dtype detection: dt[0]=1 -> fp32 floats ; dt[1]=1 -> int32 indices ----
__global__ void detect_kernel(const void* __restrict__ x, const int* __restrict__ ei,
                              int* __restrict__ dt, int E_)
{
    int t = threadIdx.x;
    const unsigned short* xb = (const unsigned short*)x;
    int f32 = 0;
    for (int i = t; i < 4096; i += 256) {
        int ex = (xb[i] >> 7) & 0xFF;   // bf16 exponent field
        if (ex > 140) f32 = 1;          // |v| > 2^13: impossible for bf16 N(0,1) data
    }
    if (f32) atomicOr(&dt[0], 1);
    int nz = 0;
    for (int i = t; i < 2048; i += 256) nz |= ei[2 * i + 1];  // int64 odd words are 0
    if (nz) atomicOr(&dt[1], 1);
}

// ---------------- K0+scatter: x@W_l/W_r GEMM with padded-CSR scatter hidden under it ----
// Phase A (pre-GEMM): read edges coalesced, fire cnt atomics, load ea rows eid-sequential
// into registers. Phase B (post-GEMM): write (src, ea-bf16) into padded-CSR slots. The
// ~8000-cycle GEMM hides atomic + load latency; ea is thus re-laid-out into dst order
// once, so node_fused never does random ea reads (R5: ~180MB of line amplification).
__global__ __launch_bounds__(128) void gemm_scatter(
    const void* __restrict__ x,
    const void* __restrict__ Wl, const void* __restrict__ bl,
    const void* __restrict__ Wr, const void* __restrict__ br,
    const void* __restrict__ ea,
    const int* __restrict__ ei, const int* __restrict__ dt,
    __hip_bfloat16* __restrict__ xl, __hip_bfloat16* __restrict__ xr,
    int* __restrict__ cnt, int* __restrict__ ovfcnt,
    int* __restrict__ src_pad, uint4* __restrict__ ea_pad, int4* __restrict__ ovf,
    int n, int E_)
{
    __shared__ float xs[NPB][128];     // 16 KB
    int t = threadIdx.x;
    int f32 = dt[0], i32 = dt[1];

    // ---- phase A: edges + atomics + ea rows (all overlap the GEMM) ----
    long eb = (long)blockIdx.x * 512;
    int sA[4], dA[4], kA[4], eA[4];
    uint4 eaR0[4], eaR1[4];
#pragma unroll
    for (int i = 0; i < 4; ++i) {
        long e = eb + i * 128 + t;
        int s = -1, d = -1;
        if (e < E_) {
            s = ldi(ei, e, i32);
            d = ldi(ei, E_ + e, i32);
            if (!((unsigned)s < (unsigned)n && (unsigned)d < (unsigned)n)) d = -1;
        }
        sA[i] = s; dA[i] = d; eA[i] = (int)e;
    }
#pragma unroll
    for (int i = 0; i < 4; ++i)
        kA[i] = (dA[i] >= 0) ? atomicAdd(&cnt[dA[i]], 1) : 0;
#pragma unroll
    for (int i = 0; i < 4; ++i) {
        eaR0[i] = make_uint4(0u, 0u, 0u, 0u); eaR1[i] = eaR0[i];
        if (dA[i] < 0) continue;
        long e = eA[i];
        if (f32) {
            const float4* q = (const float4*)ea + e * 4;
            float4 q0 = q[0], q1 = q[1], q2 = q[2], q3 = q[3];
            eaR0[i] = make_uint4(pk2(q0.x, q0.y), pk2(q0.z, q0.w),
                                 pk2(q1.x, q1.y), pk2(q1.z, q1.w));
            eaR1[i] = make_uint4(pk2(q2.x, q2.y), pk2(q2.z, q2.w),
                                 pk2(q3.x, q3.y), pk2(q3.z, q3.w));
        } else {
            const uint4* q = (const uint4*)ea + e * 2;
            eaR0[i] = q[0]; eaR1[i] = q[1];
        }
    }

    // ---- GEMM (packed f32x2: (xl, xr) channel pair per lane), NPB=32 ----
    int n0 = blockIdx.x * NPB;
    if (n0 < n) {
        for (int j = 0; j < NPB; ++j) {
            int node = n0 + j;
            xs[j][t] = (node < n) ? ldf(x, (long)node * 128 + t, f32) : 0.f;
        }
        __syncthreads();
        f32x2 acc[NPB];
#pragma unroll
        for (int j = 0; j < NPB; ++j) acc[j] = (f32x2){0.f, 0.f};
        for (int k = 0; k < 128; ++k) {
            f32x2 wlr = { ldf(Wl, k * 128 + t, f32), ldf(Wr, k * 128 + t, f32) };
#pragma unroll
            for (int j = 0; j < NPB; ++j) {
                f32x2 xv = { xs[j][k], xs[j][k] };
                acc[j] = __builtin_elementwise_fma(xv, wlr, acc[j]);
            }
        }
        float blv = ldf(bl, t, f32);
        float brv = ldf(br, t, f32);
        for (int j = 0; j < NPB; ++j) {
            int node = n0 + j;
            if (node < n) {
                xl[(long)node * 128 + t] = __float2bfloat16(acc[j].x + blv);
                xr[(long)node * 128 + t] = __float2bfloat16(acc[j].y + brv);
            }
        }
    }

    // ---- phase B: consume atomic results, write CSR slots ----
#pragma unroll
    for (int i = 0; i < 4; ++i) {
        if (dA[i] < 0) continue;
        if (kA[i] < PAD) {
            long slot = (long)dA[i] * PAD + kA[i];
            src_pad[slot] = sA[i];
            ea_pad[2 * slot]     = eaR0[i];
            ea_pad[2 * slot + 1] = eaR1[i];
        } else {
            int o = atomicAdd(ovfcnt, 1);
            if (o < OVF_CAP) ovf[o] = make_int4(dA[i], sA[i], eA[i], 0);
        }
    }
}

// per-edge attention+aggregate body: consumes bf16 ea row (E0,E1), xl dword UC;
// uses in-scope W[16], attv, w0, w1; updates acc, den.
#define EDGE_COMPUTE(E0, E1, UC)                                                       \
    {                                                                                  \
        f32x2 z = { bflo(UC) + w0, bfhi(UC) + w1 };                                    \
        z = __builtin_elementwise_fma((f32x2){bflo(E0.x), bflo(E0.x)}, W[0],  z);      \
        z = __builtin_elementwise_fma((f32x2){bfhi(E0.x), bfhi(E0.x)}, W[1],  z);      \
        z = __builtin_elementwise_fma((f32x2){bflo(E0.y), bflo(E0.y)}, W[2],  z);      \
        z = __builtin_elementwise_fma((f32x2){bfhi(E0.y), bfhi(E0.y)}, W[3],  z);      \
        z = __builtin_elementwise_fma((f32x2){bflo(E0.z), bflo(E0.z)}, W[4],  z);      \
        z = __builtin_elementwise_fma((f32x2){bfhi(E0.z), bfhi(E0.z)}, W[5],  z);      \
        z = __builtin_elementwise_fma((f32x2){bflo(E0.w), bflo(E0.w)}, W[6],  z);      \
        z = __builtin_elementwise_fma((f32x2){bfhi(E0.w), bfhi(E0.w)}, W[7],  z);      \
        z = __builtin_elementwise_fma((f32x2){bflo(E1.x), bflo(E1.x)}, W[8],  z);      \
        z = __builtin_elementwise_fma((f32x2){bfhi(E1.x), bfhi(E1.x)}, W[9],  z);      \
        z = __builtin_elementwise_fma((f32x2){bflo(E1.y), bflo(E1.y)}, W[10], z);      \
        z = __builtin_elementwise_fma((f32x2){bfhi(E1.y), bfhi(E1.y)}, W[11], z);      \
        z = __builtin_elementwise_fma((f32x2){bflo(E1.z), bflo(E1.z)}, W[12], z);      \
        z = __builtin_elementwise_fma((f32x2){bfhi(E1.z), bfhi(E1.z)}, W[13], z);      \
        z = __builtin_elementwise_fma((f32x2){bflo(E1.w), bflo(E1.w)}, W[14], z);      \
        z = __builtin_elementwise_fma((f32x2){bfhi(E1.w), bfhi(E1.w)}, W[15], z);      \
        z = __builtin_elementwise_max(z, z * 0.2f);   /* LeakyReLU(0.2) */             \
        float vv = fmaf(z.y, attv.y, z.x * attv.x);                                    \
        vv = dpp_add<0xB1>(vv);  vv = dpp_add<0x4E>(vv);                               \
        vv = dpp_add<0x124>(vv); vv = dpp_add<0x128>(vv);  /* 16-lane head sum */      \
        float exv = __expf(vv);                                                        \
        acc = __builtin_elementwise_fma((f32x2){exv, exv},                             \
                                        (f32x2){bflo(UC), bfhi(UC)}, acc);             \
        den += exv;                                                                    \
    }

// ---------------- fused node kernel: logits + softmax + aggregate + LN + residual ----------
// 1 wave per node (4 sequential nodes/wave), 2 ch/lane, padded CSR with inlined bf16 ea.
// Per edge: 1 uniform 4B src + 1 uniform 32B ea (sequential within row) + 1 xl gather.
// 1-deep software pipeline; DPP head-reduce; shfl-butterfly LN (no barriers).
__global__ __launch_bounds__(256, 2) void node_fused(
    const int* __restrict__ cnt, const int* __restrict__ src_pad,
    const uint4* __restrict__ ea_pad,
    const int4* __restrict__ ovf, const int* __restrict__ ovfcnt,
    const void* __restrict__ ea, const void* __restrict__ We, const void* __restrict__ att,
    const __hip_bfloat16* __restrict__ xl, const __hip_bfloat16* __restrict__ xr,
    const void* __restrict__ cb, const void* __restrict__ gamma,
    const void* __restrict__ beta, const void* __restrict__ x,
    const int* __restrict__ dt, float* __restrict__ out, int N_)
{
    int w = threadIdx.x >> 6, j = threadIdx.x & 63;
    int f32 = dt[0];

    f32x2 W[16];
#pragma unroll
    for (int k = 0; k < 16; ++k) {
        float2 v = ldf2(We, (long)k * 64 + j, f32);
        W[k] = (f32x2){v.x, v.y};
    }
    float2 attv = ldf2(att, j, f32);
    float2 cbv  = ldf2(cb, j, f32);
    float2 gv   = ldf2(gamma, j, f32);
    float2 bv   = ldf2(beta, j, f32);

    const unsigned* xlu = (const unsigned*)xl;
    const unsigned* xru = (const unsigned*)xr;

    for (int q = 0; q < 4; ++q) {
        int n = (blockIdx.x * 4 + w) * 4 + q;
        if (n >= N_) break;
        int deg = cnt[n];
        int m = deg < PAD ? deg : PAD;
        long base = (long)n * PAD;
        unsigned urow = xru[(long)n * 64 + j];          // xr row: once per node
        float w0 = bflo(urow), w1 = bfhi(urow);
        f32x2 acc = {0.f, 0.f};
        float den = 0.f;

        if (m > 0) {
            int sC = rfl(src_pad[base]);
            uint4 eC0 = ea_pad[2 * base], eC1 = ea_pad[2 * base + 1];
            unsigned uC = xlu[((long)sC << 6) + j];
            for (int k = 0; k < m; ++k) {
                long sl = base + ((k + 1 < m) ? k + 1 : k);   // next slot (sequential)
                int sN = rfl(src_pad[sl]);
                uint4 eN0 = ea_pad[2 * sl], eN1 = ea_pad[2 * sl + 1];
                unsigned uN = xlu[((long)sN << 6) + j];
                EDGE_COMPUTE(eC0, eC1, uC);
                sC = sN; eC0 = eN0; eC1 = eN1; uC = uN;
            }
        }
        // overflow edges (deg > PAD): astronomically rare; correct for any data
        if (deg > PAD) {
            int oc = *ovfcnt; if (oc > OVF_CAP) oc = OVF_CAP;
            for (int o = 0; o < oc; ++o) {
                int4 v4 = ovf[o];
                if (rfl(v4.x) != n) continue;
                int sO = rfl(v4.y); long eO = rfl(v4.z);
                unsigned uO = xlu[((long)sO << 6) + j];
                uint4 E0, E1;
                if (f32) {
                    const float4* qr = (const float4*)ea + eO * 4;
                    float4 q0 = qr[0], q1 = qr[1], q2 = qr[2], q3 = qr[3];
                    E0 = make_uint4(pk2(q0.x, q0.y), pk2(q0.z, q0.w),
                                    pk2(q1.x, q1.y), pk2(q1.z, q1.w));
                    E1 = make_uint4(pk2(q2.x, q2.y), pk2(q2.z, q2.w),
                                    pk2(q3.x, q3.y), pk2(q3.z, q3.w));
                } else {
                    const uint4* qr = (const uint4*)ea + eO * 2;
                    E0 = qr[0]; E1 = qr[1];
                }
                EDGE_COMPUTE(E0, E1, uO);
            }
        }

        float rden = 1.f / (den + 1e-16f);
        float o0 = acc.x * rden + cbv.x;
        float o1 = acc.y * rden + cbv.y;

        float s = o0 + o1;
#pragma unroll
        for (int o = 1; o < 64; o <<= 1) s += __shfl_xor(s, o, 64);
        float mu = s * (1.f / 128.f);
        float d0 = o0 - mu, d1 = o1 - mu;
        float vs = d0 * d0 + d1 * d1;
#pragma unroll
        for (int o = 1; o < 64; o <<= 1) vs += __shfl_xor(vs, o, 64);
        float rs = rsqrtf(vs * (1.f / 128.f) + 1e-5f);
        float2 xv = ldf2(x, (long)n * 64 + j, f32);
        float y0 = fmaxf(d0 * rs * gv.x + bv.x, 0.f) + xv.x;
        float y1 = fmaxf(d1 * rs * gv.y + bv.y, 0.f) + xv.y;
        *(float2*)(out + (long)n * 128 + 2 * j) = make_float2(y0, y1);
    }
}

extern "C" void kernel_launch(void* const* d_in, const int* in_sizes, int n_in,
                              void* d_out, int out_size, void* d_ws, size_t ws_size,
                              hipStream_t stream) {
    const void* x     = d_in[0];
    const int*  ei    = (const int*)d_in[1];
    const void* ea    = d_in[2];
    const void* Wl    = d_in[3];
    const void* bl    = d_in[4];
    const void* Wr    = d_in[5];
    const void* br    = d_in[6];
    const void* We    = d_in[7];
    const void* att   = d_in[8];
    const void* cb    = d_in[9];
    const void* gamma = d_in[10];
    const void* beta  = d_in[11];
    float* out = (float*)d_out;

    const int N_ = in_sizes[0] / 128;   // 50000
    const int E_ = in_sizes[2] / 16;    // 1600000

    size_t need = 0;
    auto sz = [&](size_t b) { size_t r = need; need += (b + 255) & ~(size_t)255; return r; };
    size_t o_xl   = sz((size_t)N_ * 128 * 2);        // 12.8 MB bf16
    size_t o_xr   = sz((size_t)N_ * 128 * 2);        // 12.8 MB bf16
    size_t o_cnt  = sz((size_t)(N_ + 8) * 4);        // cnt + ovfcnt
    size_t o_dt   = sz(256);
    size_t o_src  = sz((size_t)N_ * PAD * 4);        // 12.8 MB src slots
    size_t o_eap  = sz((size_t)N_ * PAD * 32);       // 102.4 MB bf16 ea slots
    size_t o_ovf  = sz((size_t)OVF_CAP * 16);        // 64 KB overflow list

    if (need > ws_size) {
        fail_stamp<<<1, 64, 0, stream>>>(out, 16384.f);
        return;
    }
    char* p = (char*)d_ws;
    __hip_bfloat16* xl   = (__hip_bfloat16*)(p + o_xl);
    __hip_bfloat16* xr   = (__hip_bfloat16*)(p + o_xr);
    int*   cnt           = (int*)(p + o_cnt);
    int*   ovfcnt        = cnt + N_;
    int*   dt            = (int*)(p + o_dt);
    int*   src_pad       = (int*)(p + o_src);
    uint4* ea_pad        = (uint4*)(p + o_eap);
    int4*  ovf           = (int4*)(p + o_ovf);

    zero_i<<<256, 256, 0, stream>>>(cnt, N_ + 8, dt);
    detect_kernel<<<1, 256, 0, stream>>>(x, ei, dt, E_);
    int gGemm = (N_ + NPB - 1) / NPB;
    int gScat = (E_ + 511) / 512;
    int grid0 = gGemm > gScat ? gGemm : gScat;
    gemm_scatter<<<grid0, 128, 0, stream>>>(x, Wl, bl, Wr, br, ea, ei, dt, xl, xr,
                                            cnt, ovfcnt, src_pad, ea_pad, ovf, N_, E_);
    node_fused<<<(N_ + 15) / 16, 256, 0, stream>>>(cnt, src_pad, ea_pad, ovf, ovfcnt,
                                                   ea, We, att, xl, xr,
                                                   cb, gamma, beta, x, dt, out, N_);
}

// Round 7
// 620.829 us; speedup vs baseline: 1.3729x; 1.3729x over previous
//
#include <hip/hip_runtime.h>
#include <hip/hip_bf16.h>

#define NPB 32      // nodes per block in GEMM
#define PAD 64      // padded-CSR slots per node (P(deg>64 | Poisson(32)) ~ 3e-7)
#define OVF_CAP 4096

typedef float f32x2 __attribute__((ext_vector_type(2)));

__device__ __forceinline__ float b2f(__hip_bfloat16 v) { return __bfloat162float(v); }
// float-typed harness input that may be fp32 or bf16 (dt[0] selects)
__device__ __forceinline__ float ldf(const void* p, long i, int f32) {
    return f32 ? ((const float*)p)[i] : b2f(((const __hip_bfloat16*)p)[i]);
}
// pair load: elements 2*i2, 2*i2+1 of a float-typed input (fp32 or bf16)
__device__ __forceinline__ float bflo(unsigned u) { union { unsigned i; float f; } v; v.i = u << 16; return v.f; }
__device__ __forceinline__ float bfhi(unsigned u) { union { unsigned i; float f; } v; v.i = u & 0xffff0000u; return v.f; }
__device__ __forceinline__ float2 ldf2(const void* p, long i2, int f32) {
    if (f32) return ((const float2*)p)[i2];
    unsigned u = ((const unsigned*)p)[i2];
    return make_float2(bflo(u), bfhi(u));
}
// integer harness input that may be int32 or little-endian int64 (<2^31) (dt[1] selects)
__device__ __forceinline__ int ldi(const int* p, long i, int i32) {
    return i32 ? p[i] : p[2 * i];
}
__device__ __forceinline__ int rfl(int v) { return __builtin_amdgcn_readfirstlane(v); }

// DPP-based butterfly add within a 16-lane row (pure VALU, no LDS pipe).
// CTRL: 0xB1 = quad_perm xor1, 0x4E = quad_perm xor2, 0x124 = row_ror:4, 0x128 = row_ror:8
template <int CTRL>
__device__ __forceinline__ float dpp_add(float v) {
    int s = __builtin_amdgcn_update_dpp(0, __float_as_int(v), CTRL, 0xF, 0xF, true);
    return v + __int_as_float(s);
}

// ---------------- zero ints (cnt + ovfcnt) + dt ----------------
__global__ void zero_i(int* __restrict__ a, long n, int* __restrict__ dt)
{
    long i = (long)blockIdx.x * 256 + threadIdx.x;
    long stride = (long)gridDim.x * 256;
    for (; i < n; i += stride) a[i] = 0;
    if (blockIdx.x == 0 && threadIdx.x == 0 && dt) { dt[0] = 0; dt[1] = 0; }
}

// failure-gated fp32 code write (ws-guard only)
__global__ void fail_stamp(float* __restrict__ out, float code)
{
    if (threadIdx.x == 0 && blockIdx.x == 0) out[0] = code;
}

// ---------------- dtype detection: dt[0]=1 -> fp32 floats ; dt[1]=1 -> int32 indices ----
__global__ void detect_kernel(const void* __restrict__ x, const int* __restrict__ ei,
                              int* __restrict__ dt, int E_)
{
    int t = threadIdx.x;
    const unsigned short* xb = (const unsigned short*)x;
    int f32 = 0;
    for (int i = t; i < 4096; i += 256) {
        int ex = (xb[i] >> 7) & 0xFF;   // bf16 exponent field
        if (ex > 140) f32 = 1;          // |v| > 2^13: impossible for bf16 N(0,1) data
    }
    if (f32) atomicOr(&dt[0], 1);
    int nz = 0;
    for (int i = t; i < 2048; i += 256) nz |= ei[2 * i + 1];  // int64 odd words are 0
    if (nz) atomicOr(&dt[1], 1);
}

// ---------------- K0: x_l = x@W_l + b_l ; x_r = x@W_r + b_r (packed f32x2, bf16 out) ----
__global__ __launch_bounds__(128) void gemm_xlr(
    const void* __restrict__ x,
    const void* __restrict__ Wl, const void* __restrict__ bl,
    const void* __restrict__ Wr, const void* __restrict__ br,
    const int* __restrict__ dt,
    __hip_bfloat16* __restrict__ xl, __hip_bfloat16* __restrict__ xr, int n)
{
    __shared__ float xs[NPB][128];     // 16 KB
    int f32 = dt[0];
    int t = threadIdx.x;
    int n0 = blockIdx.x * NPB;
    for (int j = 0; j < NPB; ++j) {
        int node = n0 + j;
        xs[j][t] = (node < n) ? ldf(x, (long)node * 128 + t, f32) : 0.f;
    }
    __syncthreads();
    f32x2 acc[NPB];
#pragma unroll
    for (int j = 0; j < NPB; ++j) acc[j] = (f32x2){0.f, 0.f};
    for (int k = 0; k < 128; ++k) {
        f32x2 wlr = { ldf(Wl, k * 128 + t, f32), ldf(Wr, k * 128 + t, f32) };
#pragma unroll
        for (int j = 0; j < NPB; ++j) {
            f32x2 xv = { xs[j][k], xs[j][k] };
            acc[j] = __builtin_elementwise_fma(xv, wlr, acc[j]);
        }
    }
    float blv = ldf(bl, t, f32);
    float brv = ldf(br, t, f32);
    for (int j = 0; j < NPB; ++j) {
        int node = n0 + j;
        if (node < n) {
            xl[(long)node * 128 + t] = __float2bfloat16(acc[j].x + blv);
            xr[(long)node * 128 + t] = __float2bfloat16(acc[j].y + brv);
        }
    }
}

// ---------------- padded-CSR scatter: (src, eid) 8B payload, 1 atomic per edge ----------
__global__ __launch_bounds__(256) void scatter_pad(
    const int* __restrict__ ei, const int* __restrict__ dt,
    int* __restrict__ cnt, int* __restrict__ ovfcnt,
    int2* __restrict__ se_pad, int4* __restrict__ ovf, int E_, int N_)
{
    long e = (long)blockIdx.x * 256 + threadIdx.x;
    if (e >= E_) return;
    int i32 = dt[1];
    int s = ldi(ei, e, i32);
    int d = ldi(ei, E_ + e, i32);
    if ((unsigned)s < (unsigned)N_ && (unsigned)d < (unsigned)N_) {
        int k = atomicAdd(&cnt[d], 1);
        if (k < PAD) se_pad[(long)d * PAD + k] = make_int2(s, (int)e);
        else {
            int o = atomicAdd(ovfcnt, 1);
            if (o < OVF_CAP) ovf[o] = make_int4(d, s, (int)e, 0);
        }
    }
}

// ---- per-edge attention+aggregate body (macros, NO lambdas: a by-ref lambda capture of
// W[] forced it memory-backed in R4/R5 — VGPR_Count=36 < the 32 regs W needs) ----
#define EDGE_PRE(UC)  f32x2 z = { bflo(UC) + w0, bfhi(UC) + w1 };
#define EFMA(val, idx) z = __builtin_elementwise_fma((f32x2){(val), (val)}, W[idx], z);
#define EDGE_POST(UC) \
    z = __builtin_elementwise_max(z, z * 0.2f);   /* LeakyReLU(0.2) */                 \
    float vv = fmaf(z.y, attv.y, z.x * attv.x);                                        \
    vv = dpp_add<0xB1>(vv);  vv = dpp_add<0x4E>(vv);                                   \
    vv = dpp_add<0x124>(vv); vv = dpp_add<0x128>(vv);  /* 16-lane head sum */          \
    float exv = __expf(vv);                                                            \
    acc = __builtin_elementwise_fma((f32x2){exv, exv},                                 \
                                    (f32x2){bflo(UC), bfhi(UC)}, acc);                 \
    den += exv;
#define EDGE16(E0, E1, UC) { EDGE_PRE(UC)                                              \
    EFMA(bflo(E0.x), 0)  EFMA(bfhi(E0.x), 1)  EFMA(bflo(E0.y), 2)  EFMA(bfhi(E0.y), 3) \
    EFMA(bflo(E0.z), 4)  EFMA(bfhi(E0.z), 5)  EFMA(bflo(E0.w), 6)  EFMA(bfhi(E0.w), 7) \
    EFMA(bflo(E1.x), 8)  EFMA(bfhi(E1.x), 9)  EFMA(bflo(E1.y), 10) EFMA(bfhi(E1.y), 11)\
    EFMA(bflo(E1.z), 12) EFMA(bfhi(E1.z), 13) EFMA(bflo(E1.w), 14) EFMA(bfhi(E1.w), 15)\
    EDGE_POST(UC) }
#define EDGE32(F0, F1, F2, F3, UC) { EDGE_PRE(UC)                                      \
    EFMA(F0.x, 0)  EFMA(F0.y, 1)  EFMA(F0.z, 2)  EFMA(F0.w, 3)                          \
    EFMA(F1.x, 4)  EFMA(F1.y, 5)  EFMA(F1.z, 6)  EFMA(F1.w, 7)                          \
    EFMA(F2.x, 8)  EFMA(F2.y, 9)  EFMA(F2.z, 10) EFMA(F2.w, 11)                         \
    EFMA(F3.x, 12) EFMA(F3.y, 13) EFMA(F3.z, 14) EFMA(F3.w, 15)                         \
    EDGE_POST(UC) }

// ---------------- fused node kernel: logits + softmax + aggregate + LN + residual ----------
// 1 wave per node, 2 ch/lane. Compile-time F32 split -> branch-free W loads, W resident.
// Pipeline: se prefetched 2-deep, payload (ea row + xl gather) 1-deep — the se->payload
// chain is 2 serial loads, so the split keeps both covered by compute.
template <int F32>
__device__ __forceinline__ void node_run(
    const int* __restrict__ cnt, const int2* __restrict__ se_pad,
    const int4* __restrict__ ovf, const int* __restrict__ ovfcnt,
    const void* __restrict__ ea, const void* __restrict__ We, const void* __restrict__ att,
    const unsigned* __restrict__ xlu, const unsigned* __restrict__ xru,
    const void* __restrict__ cb, const void* __restrict__ gamma,
    const void* __restrict__ beta, const void* __restrict__ x,
    float* __restrict__ out, int N_)
{
    int w = threadIdx.x >> 6, j = threadIdx.x & 63;
    int n = blockIdx.x * 4 + w;
    if (n >= N_) return;

    f32x2 W[16];
#pragma unroll
    for (int k = 0; k < 16; ++k) {
        float2 v = ldf2(We, (long)k * 64 + j, F32);
        W[k] = (f32x2){v.x, v.y};
    }
    float2 attv = ldf2(att, j, F32);
    float2 cbv  = ldf2(cb, j, F32);
    float2 gv   = ldf2(gamma, j, F32);
    float2 bv   = ldf2(beta, j, F32);

    int deg = cnt[n];
    int m = deg < PAD ? deg : PAD;
    long base = (long)n * PAD;
    unsigned urow = xru[(long)n * 64 + j];              // xr row: once per node
    float w0 = bflo(urow), w1 = bfhi(urow);
    f32x2 acc = {0.f, 0.f};
    float den = 0.f;

    if (m > 0) {
        if (F32) {
            int2 se0 = se_pad[base];
            int sA = rfl(se0.x), eA = rfl(se0.y);
            unsigned uA = xlu[((long)sA << 6) + j];
            const float4* qa = (const float4*)ea + (long)eA * 4;
            float4 f0 = qa[0], f1 = qa[1], f2 = qa[2], f3 = qa[3];
            int2 seB = se_pad[base + (m > 1 ? 1 : 0)];
            for (int k = 0; k < m; ++k) {
                int2 seC = se_pad[base + (k + 2 < m ? k + 2 : m - 1)];
                int sB = rfl(seB.x), eB = rfl(seB.y);
                unsigned uB = xlu[((long)sB << 6) + j];
                const float4* qb = (const float4*)ea + (long)eB * 4;
                float4 g0 = qb[0], g1 = qb[1], g2 = qb[2], g3 = qb[3];
                EDGE32(f0, f1, f2, f3, uA)
                seB = seC; uA = uB; f0 = g0; f1 = g1; f2 = g2; f3 = g3;
            }
        } else {
            int2 se0 = se_pad[base];
            int sA = rfl(se0.x), eA = rfl(se0.y);
            unsigned uA = xlu[((long)sA << 6) + j];
            const uint4* qa = (const uint4*)ea + (long)eA * 2;
            uint4 a0 = qa[0], a1 = qa[1];
            int2 seB = se_pad[base + (m > 1 ? 1 : 0)];
            for (int k = 0; k < m; ++k) {
                int2 seC = se_pad[base + (k + 2 < m ? k + 2 : m - 1)];
                int sB = rfl(seB.x), eB = rfl(seB.y);
                unsigned uB = xlu[((long)sB << 6) + j];
                const uint4* qb = (const uint4*)ea + (long)eB * 2;
                uint4 b0 = qb[0], b1 = qb[1];
                EDGE16(a0, a1, uA)
                seB = seC; uA = uB; a0 = b0; a1 = b1;
            }
        }
    }
    // overflow edges (deg > PAD): astronomically rare; correct for any data
    if (deg > PAD) {
        int oc = *ovfcnt; if (oc > OVF_CAP) oc = OVF_CAP;
        for (int o = 0; o < oc; ++o) {
            int4 v4 = ovf[o];
            if (rfl(v4.x) != n) continue;
            int sO = rfl(v4.y); long eO = rfl(v4.z);
            unsigned uO = xlu[((long)sO << 6) + j];
            if (F32) {
                const float4* qr = (const float4*)ea + eO * 4;
                float4 f0 = qr[0], f1 = qr[1], f2 = qr[2], f3 = qr[3];
                EDGE32(f0, f1, f2, f3, uO)
            } else {
                const uint4* qr = (const uint4*)ea + eO * 2;
                uint4 a0 = qr[0], a1 = qr[1];
                EDGE16(a0, a1, uO)
            }
        }
    }

    float rden = 1.f / (den + 1e-16f);
    float o0 = acc.x * rden + cbv.x;
    float o1 = acc.y * rden + cbv.y;

    float s = o0 + o1;
#pragma unroll
    for (int o = 1; o < 64; o <<= 1) s += __shfl_xor(s, o, 64);
    float mu = s * (1.f / 128.f);
    float d0 = o0 - mu, d1 = o1 - mu;
    float vs = d0 * d0 + d1 * d1;
#pragma unroll
    for (int o = 1; o < 64; o <<= 1) vs += __shfl_xor(vs, o, 64);
    float rs = rsqrtf(vs * (1.f / 128.f) + 1e-5f);
    float2 xv = ldf2(x, (long)n * 64 + j, F32);
    float y0 = fmaxf(d0 * rs * gv.x + bv.x, 0.f) + xv.x;
    float y1 = fmaxf(d1 * rs * gv.y + bv.y, 0.f) + xv.y;
    *(float2*)(out + (long)n * 128 + 2 * j) = make_float2(y0, y1);  // coalesced 8B store
}

__global__ __launch_bounds__(256, 4) void node_fused(
    const int* __restrict__ cnt, const int2* __restrict__ se_pad,
    const int4* __restrict__ ovf, const int* __restrict__ ovfcnt,
    const void* __restrict__ ea, const void* __restrict__ We, const void* __restrict__ att,
    const __hip_bfloat16* __restrict__ xl, const __hip_bfloat16* __restrict__ xr,
    const void* __restrict__ cb, const void* __restrict__ gamma,
    const void* __restrict__ beta, const void* __restrict__ x,
    const int* __restrict__ dt, float* __restrict__ out, int N_)
{
    const unsigned* xlu = (const unsigned*)xl;
    const unsigned* xru = (const unsigned*)xr;
    if (dt[0])
        node_run<1>(cnt, se_pad, ovf, ovfcnt, ea, We, att, xlu, xru,
                    cb, gamma, beta, x, out, N_);
    else
        node_run<0>(cnt, se_pad, ovf, ovfcnt, ea, We, att, xlu, xru,
                    cb, gamma, beta, x, out, N_);
}

extern "C" void kernel_launch(void* const* d_in, const int* in_sizes, int n_in,
                              void* d_out, int out_size, void* d_ws, size_t ws_size,
                              hipStream_t stream) {
    const void* x     = d_in[0];
    const int*  ei    = (const int*)d_in[1];
    const void* ea    = d_in[2];
    const void* Wl    = d_in[3];
    const void* bl    = d_in[4];
    const void* Wr    = d_in[5];
    const void* br    = d_in[6];
    const void* We    = d_in[7];
    const void* att   = d_in[8];
    const void* cb    = d_in[9];
    const void* gamma = d_in[10];
    const void* beta  = d_in[11];
    float* out = (float*)d_out;

    const int N_ = in_sizes[0] / 128;   // 50000
    const int E_ = in_sizes[2] / 16;    // 1600000

    size_t need = 0;
    auto sz = [&](size_t b) { size_t r = need; need += (b + 255) & ~(size_t)255; return r; };
    size_t o_xl   = sz((size_t)N_ * 128 * 2);        // 12.8 MB bf16
    size_t o_xr   = sz((size_t)N_ * 128 * 2);        // 12.8 MB bf16
    size_t o_cnt  = sz((size_t)(N_ + 8) * 4);        // cnt + ovfcnt
    size_t o_dt   = sz(256);
    size_t o_se   = sz((size_t)N_ * PAD * 8);        // 25.6 MB (src, eid) slots
    size_t o_ovf  = sz((size_t)OVF_CAP * 16);        // 64 KB overflow list

    if (need > ws_size) {
        fail_stamp<<<1, 64, 0, stream>>>(out, 16384.f);
        return;
    }
    char* p = (char*)d_ws;
    __hip_bfloat16* xl   = (__hip_bfloat16*)(p + o_xl);
    __hip_bfloat16* xr   = (__hip_bfloat16*)(p + o_xr);
    int*   cnt           = (int*)(p + o_cnt);
    int*   ovfcnt        = cnt + N_;
    int*   dt            = (int*)(p + o_dt);
    int2*  se_pad        = (int2*)(p + o_se);
    int4*  ovf           = (int4*)(p + o_ovf);

    zero_i<<<256, 256, 0, stream>>>(cnt, N_ + 8, dt);
    detect_kernel<<<1, 256, 0, stream>>>(x, ei, dt, E_);
    gemm_xlr<<<(N_ + NPB - 1) / NPB, 128, 0, stream>>>(x, Wl, bl, Wr, br, dt, xl, xr, N_);
    scatter_pad<<<(E_ + 255) / 256, 256, 0, stream>>>(ei, dt, cnt, ovfcnt,
                                                      se_pad, ovf, E_, N_);
    node_fused<<<(N_ + 3) / 4, 256, 0, stream>>>(cnt, se_pad, ovf, ovfcnt, ea, We, att,
                                                 xl, xr, cb, gamma, beta, x, dt, out, N_);
}